// Round 19
// baseline (1213.028 us; speedup 1.0000x reference)
//
#include <hip/hip_runtime.h>
#include <hip/hip_bf16.h>

#define NTOK 1024
#define HDIM 2880
#define IDIM 2880
#define NEXP 8
#define BK 64
#define NT 45  // HDIM/BK

typedef __attribute__((ext_vector_type(4))) float fx4;
typedef __attribute__((ext_vector_type(8))) short sx8;
typedef __attribute__((ext_vector_type(8))) unsigned short usx8;

typedef const __attribute__((address_space(1))) void* gas_p;
typedef __attribute__((address_space(3))) void* las_p;

__device__ __forceinline__ unsigned short f2bf(float f) {
  __hip_bfloat16 b = __float2bfloat16(f);
  return __builtin_bit_cast(unsigned short, b);
}
__device__ __forceinline__ usx8 cvt8(fx4 a, fx4 b) {
  usx8 u = {f2bf(a.x), f2bf(a.y), f2bf(a.z), f2bf(a.w),
            f2bf(b.x), f2bf(b.y), f2bf(b.z), f2bf(b.w)};
  return u;
}
__device__ __forceinline__ float bf2f(unsigned short u) {
  unsigned v = ((unsigned)u) << 16;
  return __builtin_bit_cast(float, v);
}

#define MFMA16(a, b, c) __builtin_amdgcn_mfma_f32_16x16x32_bf16(a, b, c, 0, 0, 0)
#define WAITVM(n)                                         \
  {                                                       \
    asm volatile("s_waitcnt vmcnt(" #n ")" ::: "memory"); \
    __builtin_amdgcn_sched_barrier(0);                    \
  }

__global__ __launch_bounds__(256) void rms_router_k(
    const float* __restrict__ x, const float* __restrict__ norm_w,
    const float* __restrict__ gate_w, const float* __restrict__ gate_b,
    unsigned short* __restrict__ t_bf, int* __restrict__ cnt,
    int* __restrict__ tok, int* __restrict__ tokE, int* __restrict__ tokS,
    float* __restrict__ tokW) {
  const int n = blockIdx.x;
  const int tid = threadIdx.x;
  const int wid = tid >> 6, lane = tid & 63;
  const float* xr = x + (size_t)n * HDIM;

  float ss = 0.f;
  for (int h = tid; h < HDIM; h += 256) { float v = xr[h]; ss += v * v; }
  #pragma unroll
  for (int o = 32; o > 0; o >>= 1) ss += __shfl_down(ss, o);
  __shared__ float sred[4];
  if (lane == 0) sred[wid] = ss;
  __syncthreads();
  const float rstd =
      rsqrtf((sred[0] + sred[1] + sred[2] + sred[3]) * (1.0f / HDIM) + 1e-5f);

  float p[NEXP];
  #pragma unroll
  for (int e = 0; e < NEXP; e++) p[e] = 0.f;
  for (int h = tid; h < HDIM; h += 256) {
    float xv = xr[h] * norm_w[h];
    t_bf[(size_t)n * HDIM + h] = f2bf(xv * rstd);
    #pragma unroll
    for (int e = 0; e < NEXP; e++) p[e] += xv * gate_w[e * HDIM + h];
  }
  __shared__ float pls[4][NEXP];
  #pragma unroll
  for (int e = 0; e < NEXP; e++) {
    float v = p[e];
    #pragma unroll
    for (int o = 32; o > 0; o >>= 1) v += __shfl_down(v, o);
    if (lane == 0) pls[wid][e] = v;
  }
  __syncthreads();
  if (tid == 0) {
    float lg[NEXP];
    #pragma unroll
    for (int e = 0; e < NEXP; e++)
      lg[e] = (pls[0][e] + pls[1][e] + pls[2][e] + pls[3][e]) * rstd + gate_b[e];
    unsigned used = 0;
    float val[4];
    int idx[4];
    for (int k = 0; k < 4; k++) {
      float best = -1e30f;
      int bi = 0;
      for (int e = 0; e < NEXP; e++)
        if (!((used >> e) & 1u) && lg[e] > best) { best = lg[e]; bi = e; }
      used |= 1u << bi;
      val[k] = best;
      idx[k] = bi;
    }
    float sum = 0.f, w[4];
    for (int k = 0; k < 4; k++) { w[k] = expf(val[k] - val[0]); sum += w[k]; }
    for (int k = 0; k < 4; k++) {
      int e = idx[k];
      int slot = atomicAdd(&cnt[e], 1);
      tok[e * NTOK + slot] = n;
      tokE[n * 4 + k] = e;
      tokS[n * 4 + k] = slot;
      tokW[n * 4 + k] = w[k] / sum;
    }
  }
}

// Dense-pack gathered token rows; zero-fill to 128-boundary.
__global__ __launch_bounds__(256) void pack_k(
    const unsigned short* __restrict__ t_bf, const int* __restrict__ cnt,
    const int* __restrict__ tok, unsigned short* __restrict__ a_pack) {
  const int e = blockIdx.x >> 8;
  const int r0 = (blockIdx.x & 255) * 4;
  const int ce = cnt[e];
  const int lim = (ce + 127) & ~127;
  if (r0 >= lim) return;
  const int row = r0 + (threadIdx.x >> 6);
  const int lane = threadIdx.x & 63;
  unsigned short* dst = a_pack + ((size_t)e * NTOK + row) * HDIM;
  if (row < ce) {
    const unsigned short* src = t_bf + (size_t)tok[e * NTOK + row] * HDIM;
    for (int c = lane; c < HDIM / 8; c += 64)
      *(usx8*)(dst + c * 8) = *(const usx8*)(src + c * 8);
  } else {
    const usx8 z = {0, 0, 0, 0, 0, 0, 0, 0};
    for (int c = lane; c < HDIM / 8; c += 64) *(usx8*)(dst + c * 8) = z;
  }
}

// GEMM1, BARRIER-FREE per-wave pipeline: 1 wave/block, job = 128 tokens x
// (16 G + 16 L cols). A: 16x gload_lds dbuf (L2 a_pack). B: fp32 depth-2 reg
// prefetch -> cvt -> private LDS dbuf. One counted vmcnt(24)/iter, NO
// __syncthreads. All LDS layouts = r8-verified 0-conflict XOR scheme.
__global__ __launch_bounds__(64) void gemm1_k(
    const unsigned short* __restrict__ a_pack,
    const float* __restrict__ w_gate_up, const float* __restrict__ b_gate_up,
    const int* __restrict__ cnt, unsigned short* __restrict__ act_bf) {
  const int h = blockIdx.x;
  const int z = h & 7, q = h >> 3;
  const int sl = q % 180, e = q / 180;
  const int c0 = sl * 16;  // 16 G cols (+ paired L cols at IDIM+c0)
  const int m0 = z * 128;
  const int ce = cnt[e];
  if (m0 >= ce) return;

  const int l = threadIdx.x & 63;
  const int fr = l & 15, fq = l >> 4;
  const int sw = ((l & 7) ^ ((l >> 3) & 7)) * 8;

  __shared__ __align__(16) unsigned short Ash[2][128 * 64];  // 32 KB
  __shared__ __align__(16) unsigned short Bsh[2][32 * 64];   // 8 KB (G:0-15 L:16-31)

  const fx4 FZ = {0.f, 0.f, 0.f, 0.f};
  fx4 accG[8], accL[8];
  #pragma unroll
  for (int m = 0; m < 8; m++) { accG[m] = FZ; accL[m] = FZ; }

  // A: 16 DMA instr/tile, instr j covers rows [m0+j*8, +8).
  const unsigned short* gA[16];
  #pragma unroll
  for (int j = 0; j < 16; ++j)
    gA[j] = a_pack + ((size_t)e * NTOK + m0 + j * 8 + (l >> 3)) * HDIM + sw;
  // B: 32 weight rows (16 G + 16 L); lane covers (row8=j*8+(l>>3), k8=l&7).
  const float* fB[4];
  int bO[4];
  #pragma unroll
  for (int j = 0; j < 4; ++j) {
    int r8 = j * 8 + (l >> 3);
    int wr = r8 < 16 ? (c0 + r8) : (IDIM + c0 + (r8 - 16));
    fB[j] = w_gate_up + ((size_t)e * (2 * IDIM) + wr) * HDIM + (l & 7) * 8;
    bO[j] = r8 * 64 + (((l & 7) ^ (r8 & 7)) * 8);
  }

  fx4 Ra[8], Rb[8];
  #define G1_DMA_A(kt, bb)                                                     \
    {                                                                          \
      const int _ko = (kt)*BK;                                                 \
      _Pragma("unroll") for (int j = 0; j < 16; ++j)                           \
          __builtin_amdgcn_global_load_lds((gas_p)(gA[j] + _ko),               \
                                           (las_p)&Ash[bb][(j * 8) * 64], 16,  \
                                           0, 0);                              \
    }
  #define G1_LOADB(R, kt)                                                      \
    {                                                                          \
      const int _ko = (kt)*BK;                                                 \
      _Pragma("unroll") for (int j = 0; j < 4; ++j) {                          \
        R[2 * j] = *(const fx4*)(fB[j] + _ko);                                 \
        R[2 * j + 1] = *(const fx4*)(fB[j] + _ko + 4);                         \
      }                                                                        \
    }
  #define G1_WRITEB(R, bb)                                                     \
    {                                                                          \
      _Pragma("unroll") for (int j = 0; j < 4; ++j)                            \
          *(usx8*)&Bsh[bb][bO[j]] = cvt8(R[2 * j], R[2 * j + 1]);              \
    }
  #define G1_COMPUTE(bb)                                                       \
    {                                                                          \
      _Pragma("unroll") for (int ks = 0; ks < 2; ++ks) {                       \
        const int off = ((ks * 4 + fq) ^ (fr & 7)) * 8;                        \
        sx8 aF[8], bG, bL;                                                     \
        _Pragma("unroll") for (int m = 0; m < 8; ++m) aF[m] =                  \
            *(const sx8*)&Ash[bb][(m * 16 + fr) * 64 + off];                   \
        bG = *(const sx8*)&Bsh[bb][fr * 64 + off];                             \
        bL = *(const sx8*)&Bsh[bb][(16 + fr) * 64 + off];                      \
        __builtin_amdgcn_s_setprio(1);                                         \
        _Pragma("unroll") for (int m = 0; m < 8; ++m) {                        \
          accG[m] = MFMA16(aF[m], bG, accG[m]);                                \
          accL[m] = MFMA16(aF[m], bL, accL[m]);                                \
        }                                                                      \
        __builtin_amdgcn_s_setprio(0);                                         \
      }                                                                        \
    }
  #define G1_ITER(t, RL, RW, BC, BN)                                           \
    {                                                                          \
      G1_DMA_A((t) + 1, BN);                                                   \
      const int _tl = ((t) + 2 < NT) ? (t) + 2 : 0;                            \
      G1_LOADB(RL, _tl);                                                       \
      WAITVM(24);                                                              \
      G1_WRITEB(RW, BN);                                                       \
      G1_COMPUTE(BC);                                                          \
    }

  // prologue: B(0)->Ra, A(0)->buf0, B(1)->Rb; drain B(0); stage it.
  G1_LOADB(Ra, 0);
  G1_DMA_A(0, 0);
  G1_LOADB(Rb, 1);
  WAITVM(24);
  G1_WRITEB(Ra, 0);

  for (int p = 0; p < 22; ++p) {
    G1_ITER(2 * p, Ra, Rb, 0, 1);
    G1_ITER(2 * p + 1, Rb, Ra, 1, 0);
  }
  // tail t=44 (buf0): A(44) is 16 of the 24 outstanding.
  WAITVM(8);
  G1_COMPUTE(0);

  const int colG = c0 + fr;
  const float bg = b_gate_up[e * (2 * IDIM) + colG];
  const float bl = b_gate_up[e * (2 * IDIM) + IDIM + colG];
  #pragma unroll
  for (int m = 0; m < 8; ++m) {
    #pragma unroll
    for (int r = 0; r < 4; ++r) {
      int slot = m0 + m * 16 + fq * 4 + r;
      if (slot < ce) {
        float gv = accG[m][r] + bg;
        float lv = accL[m][r] + bl;
        float a = gv * (1.0f / (1.0f + __expf(-1.702f * gv))) * (lv + 1.0f);
        act_bf[((size_t)e * NTOK + slot) * IDIM + colG] = f2bf(a);
      }
    }
  }
}

// GEMM2, same barrier-free structure: job = 128 slots x 32 h-cols.
__global__ __launch_bounds__(64) void gemm2_k(
    const unsigned short* __restrict__ act_bf, const float* __restrict__ w_down,
    const float* __restrict__ b_down, const int* __restrict__ cnt,
    unsigned short* __restrict__ outs_bf) {
  const int h = blockIdx.x;
  const int z = h & 7, q = h >> 3;
  const int sl = q % 90, e = q / 90;
  const int c0 = sl * 32;
  const int m0 = z * 128;
  const int ce = cnt[e];
  if (m0 >= ce) return;

  const int l = threadIdx.x & 63;
  const int fr = l & 15, fq = l >> 4;
  const int sw = ((l & 7) ^ ((l >> 3) & 7)) * 8;

  __shared__ __align__(16) unsigned short Ash[2][128 * 64];  // 32 KB
  __shared__ __align__(16) unsigned short Bsh[2][32 * 64];   // 8 KB

  const fx4 FZ = {0.f, 0.f, 0.f, 0.f};
  fx4 acc0[8], acc1[8];
  #pragma unroll
  for (int m = 0; m < 8; m++) { acc0[m] = FZ; acc1[m] = FZ; }

  const unsigned short* gA[16];
  #pragma unroll
  for (int j = 0; j < 16; ++j)
    gA[j] = act_bf + ((size_t)e * NTOK + m0 + j * 8 + (l >> 3)) * IDIM + sw;
  const float* fB[4];
  int bO[4];
  #pragma unroll
  for (int j = 0; j < 4; ++j) {
    int r8 = j * 8 + (l >> 3);
    fB[j] = w_down + ((size_t)e * HDIM + c0 + r8) * IDIM + (l & 7) * 8;
    bO[j] = r8 * 64 + (((l & 7) ^ (r8 & 7)) * 8);
  }

  fx4 Ra[8], Rb[8];
  #define G2_DMA_A(kt, bb)                                                     \
    {                                                                          \
      const int _ko = (kt)*BK;                                                 \
      _Pragma("unroll") for (int j = 0; j < 16; ++j)                           \
          __builtin_amdgcn_global_load_lds((gas_p)(gA[j] + _ko),               \
                                           (las_p)&Ash[bb][(j * 8) * 64], 16,  \
                                           0, 0);                              \
    }
  #define G2_LOADB(R, kt)                                                      \
    {                                                                          \
      const int _ko = (kt)*BK;                                                 \
      _Pragma("unroll") for (int j = 0; j < 4; ++j) {                          \
        R[2 * j] = *(const fx4*)(fB[j] + _ko);                                 \
        R[2 * j + 1] = *(const fx4*)(fB[j] + _ko + 4);                         \
      }                                                                        \
    }
  #define G2_WRITEB(R, bb)                                                     \
    {                                                                          \
      _Pragma("unroll") for (int j = 0; j < 4; ++j)                            \
          *(usx8*)&Bsh[bb][bO[j]] = cvt8(R[2 * j], R[2 * j + 1]);              \
    }
  #define G2_COMPUTE(bb)                                                       \
    {                                                                          \
      _Pragma("unroll") for (int ks = 0; ks < 2; ++ks) {                       \
        const int off = ((ks * 4 + fq) ^ (fr & 7)) * 8;                        \
        sx8 aF[8], b0, b1;                                                     \
        _Pragma("unroll") for (int m = 0; m < 8; ++m) aF[m] =                  \
            *(const sx8*)&Ash[bb][(m * 16 + fr) * 64 + off];                   \
        b0 = *(const sx8*)&Bsh[bb][fr * 64 + off];                             \
        b1 = *(const sx8*)&Bsh[bb][(16 + fr) * 64 + off];                      \
        __builtin_amdgcn_s_setprio(1);                                         \
        _Pragma("unroll") for (int m = 0; m < 8; ++m) {                        \
          acc0[m] = MFMA16(aF[m], b0, acc0[m]);                                \
          acc1[m] = MFMA16(aF[m], b1, acc1[m]);                                \
        }                                                                      \
        __builtin_amdgcn_s_setprio(0);                                         \
      }                                                                        \
    }
  #define G2_ITER(t, RL, RW, BC, BN)                                           \
    {                                                                          \
      G2_DMA_A((t) + 1, BN);                                                   \
      const int _tl = ((t) + 2 < NT) ? (t) + 2 : 0;                            \
      G2_LOADB(RL, _tl);                                                       \
      WAITVM(24);                                                              \
      G2_WRITEB(RW, BN);                                                       \
      G2_COMPUTE(BC);                                                          \
    }

  G2_LOADB(Ra, 0);
  G2_DMA_A(0, 0);
  G2_LOADB(Rb, 1);
  WAITVM(24);
  G2_WRITEB(Ra, 0);

  for (int p = 0; p < 22; ++p) {
    G2_ITER(2 * p, Ra, Rb, 0, 1);
    G2_ITER(2 * p + 1, Rb, Ra, 1, 0);
  }
  WAITVM(8);
  G2_COMPUTE(0);

  #pragma unroll
  for (int n = 0; n < 2; ++n) {
    const int col = c0 + n * 16 + fr;
    const float bias = b_down[e * HDIM + col];
    #pragma unroll
    for (int m = 0; m < 8; ++m) {
      #pragma unroll
      for (int r = 0; r < 4; ++r) {
        int slot = m0 + m * 16 + fq * 4 + r;
        if (slot < ce)
          outs_bf[((size_t)e * NTOK + slot) * HDIM + col] =
              f2bf((n == 0 ? acc0[m][r] : acc1[m][r]) + bias);
      }
    }
  }
}

// combine: out[n] = x[n] + sum_k w_k * outs_bf[e_k, s_k]
__global__ __launch_bounds__(256) void combine_k(
    const float* __restrict__ x, const unsigned short* __restrict__ outs_bf,
    const int* __restrict__ tokE, const int* __restrict__ tokS,
    const float* __restrict__ tokW, float* __restrict__ out) {
  const int n = blockIdx.x;
  const unsigned short* src[4];
  float w[4];
  #pragma unroll
  for (int k = 0; k < 4; ++k) {
    int e = tokE[n * 4 + k], s = tokS[n * 4 + k];
    w[k] = tokW[n * 4 + k];
    src[k] = outs_bf + ((size_t)e * NTOK + s) * HDIM;
  }
  const float* xr = x + (size_t)n * HDIM;
  float* orow = out + (size_t)n * HDIM;
  for (int c = threadIdx.x; c < HDIM / 8; c += 256) {
    fx4 lo = *(const fx4*)(xr + c * 8);
    fx4 hi = *(const fx4*)(xr + c * 8 + 4);
    #pragma unroll
    for (int k = 0; k < 4; ++k) {
      usx8 v = *(const usx8*)(src[k] + c * 8);
      lo.x += w[k] * bf2f(v[0]);
      lo.y += w[k] * bf2f(v[1]);
      lo.z += w[k] * bf2f(v[2]);
      lo.w += w[k] * bf2f(v[3]);
      hi.x += w[k] * bf2f(v[4]);
      hi.y += w[k] * bf2f(v[5]);
      hi.z += w[k] * bf2f(v[6]);
      hi.w += w[k] * bf2f(v[7]);
    }
    *(fx4*)(orow + c * 8) = lo;
    *(fx4*)(orow + c * 8 + 4) = hi;
  }
}

extern "C" void kernel_launch(void* const* d_in, const int* in_sizes, int n_in,
                              void* d_out, int out_size, void* d_ws,
                              size_t ws_size, hipStream_t stream) {
  const float* x = (const float*)d_in[0];
  const float* norm_w = (const float*)d_in[1];
  const float* gate_w = (const float*)d_in[2];
  const float* gate_b = (const float*)d_in[3];
  const float* w_gate_up = (const float*)d_in[4];
  const float* b_gate_up = (const float*)d_in[5];
  const float* w_down = (const float*)d_in[6];
  const float* b_down = (const float*)d_in[7];
  float* out = (float*)d_out;

  char* ws = (char*)d_ws;
  size_t off = 0;
  unsigned short* t_bf = (unsigned short*)(ws + off);
  off += (size_t)NTOK * HDIM * 2;
  unsigned short* a_pack = (unsigned short*)(ws + off);
  off += (size_t)NEXP * NTOK * HDIM * 2;
  unsigned short* act_bf = (unsigned short*)(ws + off);
  off += (size_t)NEXP * NTOK * IDIM * 2;
  unsigned short* outs_bf = (unsigned short*)(ws + off);
  off += (size_t)NEXP * NTOK * HDIM * 2;
  int* cnt = (int*)(ws + off);
  off += 256;
  int* tok = (int*)(ws + off);
  off += (size_t)NEXP * NTOK * 4;
  int* tokE = (int*)(ws + off);
  off += (size_t)NTOK * 4 * 4;
  int* tokS = (int*)(ws + off);
  off += (size_t)NTOK * 4 * 4;
  float* tokW = (float*)(ws + off);
  off += (size_t)NTOK * 4 * 4;

  hipMemsetAsync(cnt, 0, NEXP * sizeof(int), stream);
  rms_router_k<<<NTOK, 256, 0, stream>>>(x, norm_w, gate_w, gate_b, t_bf, cnt,
                                         tok, tokE, tokS, tokW);
  pack_k<<<NEXP * 256, 256, 0, stream>>>(t_bf, cnt, tok, a_pack);
  // 1-wave blocks; barrier-free per-wave pipelines. z fastest -> the 4-8
  // token-group twins of a weight panel are adjacent (L3-shared, ~94 MB set).
  gemm1_k<<<8 * 180 * 8, 64, 0, stream>>>(a_pack, w_gate_up, b_gate_up, cnt,
                                          act_bf);
  gemm2_k<<<8 * 90 * 8, 64, 0, stream>>>(act_bf, w_down, b_down, cnt, outs_bf);
  combine_k<<<NTOK, 256, 0, stream>>>(x, outs_bf, tokE, tokS, tokW, out);
}

// Round 20
// 589.906 us; speedup vs baseline: 2.0563x; 2.0563x over previous
//
#include <hip/hip_runtime.h>
#include <hip/hip_bf16.h>

#define NTOK 1024
#define HDIM 2880
#define IDIM 2880
#define NEXP 8
#define BK 64
#define NT 45  // HDIM/BK

typedef __attribute__((ext_vector_type(4))) float fx4;
typedef __attribute__((ext_vector_type(16))) float fx16;
typedef __attribute__((ext_vector_type(8))) short sx8;
typedef __attribute__((ext_vector_type(8))) unsigned short usx8;

typedef const __attribute__((address_space(1))) void* gas_p;
typedef __attribute__((address_space(3))) void* las_p;

__device__ __forceinline__ unsigned short f2bf(float f) {
  __hip_bfloat16 b = __float2bfloat16(f);
  return __builtin_bit_cast(unsigned short, b);
}
__device__ __forceinline__ usx8 cvt8(fx4 a, fx4 b) {
  usx8 u = {f2bf(a.x), f2bf(a.y), f2bf(a.z), f2bf(a.w),
            f2bf(b.x), f2bf(b.y), f2bf(b.z), f2bf(b.w)};
  return u;
}
__device__ __forceinline__ float bf2f(unsigned short u) {
  unsigned v = ((unsigned)u) << 16;
  return __builtin_bit_cast(float, v);
}

#define MFMA32(a, b, c) __builtin_amdgcn_mfma_f32_32x32x16_bf16(a, b, c, 0, 0, 0)

__global__ __launch_bounds__(256) void rms_router_k(
    const float* __restrict__ x, const float* __restrict__ norm_w,
    const float* __restrict__ gate_w, const float* __restrict__ gate_b,
    unsigned short* __restrict__ t_bf, int* __restrict__ cnt,
    int* __restrict__ tok, int* __restrict__ tokE, int* __restrict__ tokS,
    float* __restrict__ tokW) {
  const int n = blockIdx.x;
  const int tid = threadIdx.x;
  const int wid = tid >> 6, lane = tid & 63;
  const float* xr = x + (size_t)n * HDIM;

  float ss = 0.f;
  for (int h = tid; h < HDIM; h += 256) { float v = xr[h]; ss += v * v; }
  #pragma unroll
  for (int o = 32; o > 0; o >>= 1) ss += __shfl_down(ss, o);
  __shared__ float sred[4];
  if (lane == 0) sred[wid] = ss;
  __syncthreads();
  const float rstd =
      rsqrtf((sred[0] + sred[1] + sred[2] + sred[3]) * (1.0f / HDIM) + 1e-5f);

  float p[NEXP];
  #pragma unroll
  for (int e = 0; e < NEXP; e++) p[e] = 0.f;
  for (int h = tid; h < HDIM; h += 256) {
    float xv = xr[h] * norm_w[h];
    t_bf[(size_t)n * HDIM + h] = f2bf(xv * rstd);
    #pragma unroll
    for (int e = 0; e < NEXP; e++) p[e] += xv * gate_w[e * HDIM + h];
  }
  __shared__ float pls[4][NEXP];
  #pragma unroll
  for (int e = 0; e < NEXP; e++) {
    float v = p[e];
    #pragma unroll
    for (int o = 32; o > 0; o >>= 1) v += __shfl_down(v, o);
    if (lane == 0) pls[wid][e] = v;
  }
  __syncthreads();
  if (tid == 0) {
    float lg[NEXP];
    #pragma unroll
    for (int e = 0; e < NEXP; e++)
      lg[e] = (pls[0][e] + pls[1][e] + pls[2][e] + pls[3][e]) * rstd + gate_b[e];
    unsigned used = 0;
    float val[4];
    int idx[4];
    for (int k = 0; k < 4; k++) {
      float best = -1e30f;
      int bi = 0;
      for (int e = 0; e < NEXP; e++)
        if (!((used >> e) & 1u) && lg[e] > best) { best = lg[e]; bi = e; }
      used |= 1u << bi;
      val[k] = best;
      idx[k] = bi;
    }
    float sum = 0.f, w[4];
    for (int k = 0; k < 4; k++) { w[k] = expf(val[k] - val[0]); sum += w[k]; }
    for (int k = 0; k < 4; k++) {
      int e = idx[k];
      int slot = atomicAdd(&cnt[e], 1);
      tok[e * NTOK + slot] = n;
      tokE[n * 4 + k] = e;
      tokS[n * 4 + k] = slot;
      tokW[n * 4 + k] = w[k] / sum;
    }
  }
}

// Dense-pack gathered token rows; zero-fill to 128-boundary.
__global__ __launch_bounds__(256) void pack_k(
    const unsigned short* __restrict__ t_bf, const int* __restrict__ cnt,
    const int* __restrict__ tok, unsigned short* __restrict__ a_pack) {
  const int e = blockIdx.x >> 8;
  const int r0 = (blockIdx.x & 255) * 4;
  const int ce = cnt[e];
  const int lim = (ce + 127) & ~127;
  if (r0 >= lim) return;
  const int row = r0 + (threadIdx.x >> 6);
  const int lane = threadIdx.x & 63;
  unsigned short* dst = a_pack + ((size_t)e * NTOK + row) * HDIM;
  if (row < ce) {
    const unsigned short* src = t_bf + (size_t)tok[e * NTOK + row] * HDIM;
    for (int c = lane; c < HDIM / 8; c += 64)
      *(usx8*)(dst + c * 8) = *(const usx8*)(src + c * 8);
  } else {
    const usx8 z = {0, 0, 0, 0, 0, 0, 0, 0};
    for (int c = lane; c < HDIM / 8; c += 64) *(usx8*)(dst + c * 8) = z;
  }
}

// GEMM1 (r15 scaffold, 32x32x16 MFMA): 128 slots x 64 I-cols x {G,L}, BK=64,
// 4 waves (2m x 2n); wave = 64 rows x 32 cols (both G,L halves).
// A: dense bf16 DMA. B: fp32 fetch-once, reg-prefetch after ready-barrier,
// in-loop cvt. XOR chunk^(row&7) layout (bank-balanced at 32x32 reads).
__global__ __launch_bounds__(256, 3) void gemm1_k(
    const unsigned short* __restrict__ a_pack,
    const float* __restrict__ w_gate_up, const float* __restrict__ b_gate_up,
    const int* __restrict__ cnt, unsigned short* __restrict__ act_bf) {
  const int h = blockIdx.x;
  const int u = (h >> 6) * 8 + (h & 7);  // (e, col-slice) < 360
  const int z = (h >> 3) & 7;
  const int e = u / 45;
  const int c0 = (u % 45) * 64;
  const int m0 = z * 128;
  const int ce = cnt[e];
  if (m0 >= ce) return;

  const int tid = threadIdx.x, l = tid & 63, wid = tid >> 6;
  const int wm = wid >> 1, wn = wid & 1;
  const int l7 = l & 7, koct = l >> 5, l31 = l & 31;
  const int sw = (l7 ^ ((l >> 3) & 7)) * 8;

  __shared__ __align__(16) unsigned short Ash[128 * 64];  // 16 KB
  __shared__ __align__(16) unsigned short Bsh[128 * 64];  // 16 KB (G:0-63 L:64-127)

  const fx16 FZ16 = {0.f, 0.f, 0.f, 0.f, 0.f, 0.f, 0.f, 0.f,
                     0.f, 0.f, 0.f, 0.f, 0.f, 0.f, 0.f, 0.f};
  fx16 accG[2], accL[2];  // [mb] over two 32-row sub-blocks
  accG[0] = FZ16; accG[1] = FZ16; accL[0] = FZ16; accL[1] = FZ16;

  // A: dense consecutive rows; 4 DMA/thread, 8 rows per instr.
  const unsigned short* gA[4];
  #pragma unroll
  for (int j = 0; j < 4; ++j) {
    int row = m0 + wid * 32 + j * 8 + (l >> 3);
    gA[j] = a_pack + ((size_t)e * NTOK + row) * HDIM + sw;
  }
  // B: 128 rows (64 G + 64 L) x 8 chunks = 1024 slots; 4 slots/thread.
  const float* fB[4];
  int bO[4];
  #pragma unroll
  for (int q = 0; q < 4; ++q) {
    int s = tid + 256 * q;
    int bR = s >> 3, bC = s & 7;
    int wr = bR < 64 ? (c0 + bR) : (IDIM + c0 + (bR - 64));
    fB[q] = w_gate_up + ((size_t)e * (2 * IDIM) + wr) * HDIM + bC * 8;
    bO[q] = bR * 64 + ((bC ^ (bR & 7)) * 8);
  }

  fx4 Ra[8];
  #pragma unroll
  for (int q = 0; q < 4; ++q) {
    Ra[2 * q] = *(const fx4*)(fB[q]);
    Ra[2 * q + 1] = *(const fx4*)(fB[q] + 4);
  }

  for (int t = 0; t < NT; ++t) {
    const int ko = t * BK;
    __syncthreads();  // previous tile consumed
    #pragma unroll
    for (int j = 0; j < 4; ++j)
      __builtin_amdgcn_global_load_lds((gas_p)(gA[j] + ko),
                                       (las_p)&Ash[(wid * 32 + j * 8) * 64], 16,
                                       0, 0);
    #pragma unroll
    for (int q = 0; q < 4; ++q)
      *(usx8*)&Bsh[bO[q]] = cvt8(Ra[2 * q], Ra[2 * q + 1]);
    __syncthreads();  // tile ready (drain covered by co-resident blocks)
    if (t + 1 < NT) {
      const int kf = (t + 1) * BK;
      #pragma unroll
      for (int q = 0; q < 4; ++q) {
        Ra[2 * q] = *(const fx4*)(fB[q] + kf);
        Ra[2 * q + 1] = *(const fx4*)(fB[q] + kf + 4);
      }
    }
    #pragma unroll
    for (int ks = 0; ks < 4; ++ks) {  // K = 4 x 16
      const int c = ks * 2 + koct;
      const int off = (c ^ l7) * 8;
      sx8 aF[2], bG, bL;
      #pragma unroll
      for (int mb = 0; mb < 2; ++mb)
        aF[mb] = *(const sx8*)&Ash[(wm * 64 + mb * 32 + l31) * 64 + off];
      bG = *(const sx8*)&Bsh[(wn * 32 + l31) * 64 + off];
      bL = *(const sx8*)&Bsh[(64 + wn * 32 + l31) * 64 + off];
      __builtin_amdgcn_s_setprio(1);
      #pragma unroll
      for (int mb = 0; mb < 2; ++mb) {
        accG[mb] = MFMA32(aF[mb], bG, accG[mb]);
        accL[mb] = MFMA32(aF[mb], bL, accL[mb]);
      }
      __builtin_amdgcn_s_setprio(0);
    }
  }

  const int col = c0 + wn * 32 + l31;
  const float bg = b_gate_up[e * (2 * IDIM) + col];
  const float bl = b_gate_up[e * (2 * IDIM) + IDIM + col];
  #pragma unroll
  for (int mb = 0; mb < 2; ++mb) {
    #pragma unroll
    for (int r = 0; r < 16; ++r) {
      int slot = m0 + wm * 64 + mb * 32 + (r & 3) + 8 * (r >> 2) + 4 * koct;
      if (slot < ce) {
        float gv = accG[mb][r] + bg;
        float lv = accL[mb][r] + bl;
        float a = gv * (1.0f / (1.0f + __expf(-1.702f * gv))) * (lv + 1.0f);
        act_bf[((size_t)e * NTOK + slot) * IDIM + col] = f2bf(a);
      }
    }
  }
}

// GEMM2 (r15 scaffold, 32x32x16): 128 slots x 64 cols, BK=64, 4 waves
// (2m x 2n); wave = 64 x 32. Dense epilogue (no atomics).
__global__ __launch_bounds__(256, 3) void gemm2_k(
    const unsigned short* __restrict__ act_bf, const float* __restrict__ w_down,
    const float* __restrict__ b_down, const int* __restrict__ cnt,
    unsigned short* __restrict__ outs_bf) {
  const int h = blockIdx.x;
  const int u = (h >> 6) * 8 + (h & 7);  // < 360
  const int z = (h >> 3) & 7;
  const int e = u / 45;
  const int c0 = (u % 45) * 64;
  const int m0 = z * 128;
  const int ce = cnt[e];
  if (m0 >= ce) return;

  const int tid = threadIdx.x, l = tid & 63, wid = tid >> 6;
  const int wm = wid >> 1, wn = wid & 1;
  const int l7 = l & 7, koct = l >> 5, l31 = l & 31;
  const int sw = (l7 ^ ((l >> 3) & 7)) * 8;

  __shared__ __align__(16) unsigned short Ash[128 * 64];  // 16 KB
  __shared__ __align__(16) unsigned short Bsh[64 * 64];   // 8 KB

  const fx16 FZ16 = {0.f, 0.f, 0.f, 0.f, 0.f, 0.f, 0.f, 0.f,
                     0.f, 0.f, 0.f, 0.f, 0.f, 0.f, 0.f, 0.f};
  fx16 acc[2];
  acc[0] = FZ16; acc[1] = FZ16;

  const unsigned short* gA[4];
  #pragma unroll
  for (int j = 0; j < 4; ++j) {
    int row = m0 + wid * 32 + j * 8 + (l >> 3);
    gA[j] = act_bf + ((size_t)e * NTOK + row) * IDIM + sw;
  }
  // B: 64 rows x 8 chunks = 512 slots; 2 slots/thread.
  const float* fB[2];
  int bO[2];
  #pragma unroll
  for (int q = 0; q < 2; ++q) {
    int s = tid + 256 * q;
    int bR = s >> 3, bC = s & 7;
    fB[q] = w_down + ((size_t)e * HDIM + c0 + bR) * IDIM + bC * 8;
    bO[q] = bR * 64 + ((bC ^ (bR & 7)) * 8);
  }

  fx4 Ra[4];
  #pragma unroll
  for (int q = 0; q < 2; ++q) {
    Ra[2 * q] = *(const fx4*)(fB[q]);
    Ra[2 * q + 1] = *(const fx4*)(fB[q] + 4);
  }

  for (int t = 0; t < NT; ++t) {
    const int ko = t * BK;
    __syncthreads();
    #pragma unroll
    for (int j = 0; j < 4; ++j)
      __builtin_amdgcn_global_load_lds((gas_p)(gA[j] + ko),
                                       (las_p)&Ash[(wid * 32 + j * 8) * 64], 16,
                                       0, 0);
    #pragma unroll
    for (int q = 0; q < 2; ++q)
      *(usx8*)&Bsh[bO[q]] = cvt8(Ra[2 * q], Ra[2 * q + 1]);
    __syncthreads();
    if (t + 1 < NT) {
      const int kf = (t + 1) * BK;
      #pragma unroll
      for (int q = 0; q < 2; ++q) {
        Ra[2 * q] = *(const fx4*)(fB[q] + kf);
        Ra[2 * q + 1] = *(const fx4*)(fB[q] + kf + 4);
      }
    }
    #pragma unroll
    for (int ks = 0; ks < 4; ++ks) {
      const int c = ks * 2 + koct;
      const int off = (c ^ l7) * 8;
      sx8 aF[2], bB;
      #pragma unroll
      for (int mb = 0; mb < 2; ++mb)
        aF[mb] = *(const sx8*)&Ash[(wm * 64 + mb * 32 + l31) * 64 + off];
      bB = *(const sx8*)&Bsh[(wn * 32 + l31) * 64 + off];
      __builtin_amdgcn_s_setprio(1);
      #pragma unroll
      for (int mb = 0; mb < 2; ++mb) acc[mb] = MFMA32(aF[mb], bB, acc[mb]);
      __builtin_amdgcn_s_setprio(0);
    }
  }

  const int col = c0 + wn * 32 + l31;
  const float bias = b_down[e * HDIM + col];
  #pragma unroll
  for (int mb = 0; mb < 2; ++mb) {
    #pragma unroll
    for (int r = 0; r < 16; ++r) {
      int slot = m0 + wm * 64 + mb * 32 + (r & 3) + 8 * (r >> 2) + 4 * koct;
      if (slot < ce)
        outs_bf[((size_t)e * NTOK + slot) * HDIM + col] =
            f2bf(acc[mb][r] + bias);
    }
  }
}

// combine: out[n] = x[n] + sum_k w_k * outs_bf[e_k, s_k]
__global__ __launch_bounds__(256) void combine_k(
    const float* __restrict__ x, const unsigned short* __restrict__ outs_bf,
    const int* __restrict__ tokE, const int* __restrict__ tokS,
    const float* __restrict__ tokW, float* __restrict__ out) {
  const int n = blockIdx.x;
  const unsigned short* src[4];
  float w[4];
  #pragma unroll
  for (int k = 0; k < 4; ++k) {
    int e = tokE[n * 4 + k], s = tokS[n * 4 + k];
    w[k] = tokW[n * 4 + k];
    src[k] = outs_bf + ((size_t)e * NTOK + s) * HDIM;
  }
  const float* xr = x + (size_t)n * HDIM;
  float* orow = out + (size_t)n * HDIM;
  for (int c = threadIdx.x; c < HDIM / 8; c += 256) {
    fx4 lo = *(const fx4*)(xr + c * 8);
    fx4 hi = *(const fx4*)(xr + c * 8 + 4);
    #pragma unroll
    for (int k = 0; k < 4; ++k) {
      usx8 v = *(const usx8*)(src[k] + c * 8);
      lo.x += w[k] * bf2f(v[0]);
      lo.y += w[k] * bf2f(v[1]);
      lo.z += w[k] * bf2f(v[2]);
      lo.w += w[k] * bf2f(v[3]);
      hi.x += w[k] * bf2f(v[4]);
      hi.y += w[k] * bf2f(v[5]);
      hi.z += w[k] * bf2f(v[6]);
      hi.w += w[k] * bf2f(v[7]);
    }
    *(fx4*)(orow + c * 8) = lo;
    *(fx4*)(orow + c * 8 + 4) = hi;
  }
}

extern "C" void kernel_launch(void* const* d_in, const int* in_sizes, int n_in,
                              void* d_out, int out_size, void* d_ws,
                              size_t ws_size, hipStream_t stream) {
  const float* x = (const float*)d_in[0];
  const float* norm_w = (const float*)d_in[1];
  const float* gate_w = (const float*)d_in[2];
  const float* gate_b = (const float*)d_in[3];
  const float* w_gate_up = (const float*)d_in[4];
  const float* b_gate_up = (const float*)d_in[5];
  const float* w_down = (const float*)d_in[6];
  const float* b_down = (const float*)d_in[7];
  float* out = (float*)d_out;

  char* ws = (char*)d_ws;
  size_t off = 0;
  unsigned short* t_bf = (unsigned short*)(ws + off);
  off += (size_t)NTOK * HDIM * 2;
  unsigned short* a_pack = (unsigned short*)(ws + off);
  off += (size_t)NEXP * NTOK * HDIM * 2;
  unsigned short* act_bf = (unsigned short*)(ws + off);
  off += (size_t)NEXP * NTOK * IDIM * 2;
  unsigned short* outs_bf = (unsigned short*)(ws + off);
  off += (size_t)NEXP * NTOK * HDIM * 2;
  int* cnt = (int*)(ws + off);
  off += 256;
  int* tok = (int*)(ws + off);
  off += (size_t)NEXP * NTOK * 4;
  int* tokE = (int*)(ws + off);
  off += (size_t)NTOK * 4 * 4;
  int* tokS = (int*)(ws + off);
  off += (size_t)NTOK * 4 * 4;
  float* tokW = (float*)(ws + off);
  off += (size_t)NTOK * 4 * 4;

  hipMemsetAsync(cnt, 0, NEXP * sizeof(int), stream);
  rms_router_k<<<NTOK, 256, 0, stream>>>(x, norm_w, gate_w, gate_b, t_bf, cnt,
                                         tok, tokE, tokS, tokW);
  pack_k<<<NEXP * 256, 256, 0, stream>>>(t_bf, cnt, tok, a_pack);
  // h = g*64 + z*8 + v : z-twins of one (e,c) share h%8 (same XCD) within a
  // 64-block window -> weight panel HBM-fetched once (r15-measured best).
  gemm1_k<<<2880, 256, 0, stream>>>(a_pack, w_gate_up, b_gate_up, cnt, act_bf);
  gemm2_k<<<2880, 256, 0, stream>>>(act_bf, w_down, b_down, cnt, outs_bf);
  combine_k<<<NTOK, 256, 0, stream>>>(x, outs_bf, tokE, tokS, tokW, out);
}